// Round 2
// baseline (159.253 us; speedup 1.0000x reference)
//
#include <hip/hip_runtime.h>
#include <hip/hip_bf16.h>

// ScaledDotProductAttentionEnriched: BH=64, S=1024, DK=64, FG=FL=32.
// Two-pass: (1) prep kernel converts K-enriched (+mask bias col, pre-scaled)
// and V-transposed tiles to bf16 once into d_ws, laid out as the exact LDS
// image; (2) flash-attention main kernel with async global_load_lds staging,
// no-max softmax (exp2 raw; scores can't overflow), split q-half x k-half
// across the 4 waves, epilogue combine through LDS.

#define BHn 64
#define Sn  1024
#define NT  16          // number of 64-wide k tiles
#define BK  64
#define BQ  64
#define KSTR 152        // K-enriched row stride (bf16): 144 cols + 8 pad
#define VSTR 72         // Vt row stride (bf16): 64 cols + 8 pad (16B-aligned rows)
#define KTILE (BK*KSTR*2)    // 19456 B = 19 chunks of 1024
#define VTILE (64*VSTR*2)    // 9216 B  = 9 chunks of 1024
#define OSTR 68

typedef __attribute__((ext_vector_type(8)))  __bf16 bf16x8;
typedef __attribute__((ext_vector_type(16))) float  f32x16;
typedef __attribute__((ext_vector_type(4)))  unsigned int u32x4;
typedef __attribute__((ext_vector_type(2)))  unsigned int u32x2;

__device__ __forceinline__ unsigned f2bf1(float a){
    union { float f; unsigned u; } c; c.f = a;
    return (c.u + 0x7fffu + ((c.u >> 16) & 1u)) >> 16;   // RNE f32->bf16
}
__device__ __forceinline__ unsigned f2bf2(float a, float b){
    return f2bf1(a) | (f2bf1(b) << 16);
}
__device__ __forceinline__ void wr4(unsigned short* p, float4 f){
    u32x2 w; w.x = f2bf2(f.x, f.y); w.y = f2bf2(f.z, f.w);
    *(u32x2*)p = w;
}
// pack (bf16_trunc(b) << 16) | bf16_trunc(a) in one v_perm_b32
__device__ __forceinline__ unsigned pkbf(float a, float b){
    return __builtin_amdgcn_perm(__builtin_bit_cast(unsigned, b),
                                 __builtin_bit_cast(unsigned, a), 0x07060302u);
}
__device__ __forceinline__ void gld_lds16(const void* g, void* l){
    __builtin_amdgcn_global_load_lds(
        (const __attribute__((address_space(1))) unsigned int*)g,
        (__attribute__((address_space(3))) unsigned int*)l, 16, 0, 0);
}

// ---------------- prep: fp32 -> bf16 tile images in d_ws ----------------
__global__ __launch_bounds__(256)
void attn_prep(const float* __restrict__ K, const float* __restrict__ V,
               const float* __restrict__ LF, const float* __restrict__ GF,
               const int* __restrict__ M,
               unsigned short* __restrict__ Kp, unsigned short* __restrict__ Vp)
{
    __shared__ float vlds[64*65];
    const int tid = threadIdx.x;
    const int bh = blockIdx.x >> 4, ti = blockIdx.x & 15;
    const int kb = ti * BK;
    unsigned short* ktg = Kp + (size_t)(bh*NT + ti) * (BK*KSTR);
    unsigned int*   vtg = (unsigned int*)(Vp + (size_t)(bh*NT + ti) * (64*VSTR));

    // V -> LDS as [d][k] (stride 65: transposed reads conflict-free)
    #pragma unroll
    for (int i=0;i<4;i++){
        int idx = tid + 256*i, k = idx>>4, c = idx&15;
        float4 f = *(const float4*)(V + ((size_t)bh*Sn + kb + k)*64 + c*4);
        vlds[(c*4+0)*65 + k] = f.x;
        vlds[(c*4+1)*65 + k] = f.y;
        vlds[(c*4+2)*65 + k] = f.z;
        vlds[(c*4+3)*65 + k] = f.w;
    }
    // K cols 0..63
    #pragma unroll
    for (int i=0;i<4;i++){
        int idx = tid + 256*i, row = idx>>4, c = idx&15;
        float4 f = *(const float4*)(K + ((size_t)bh*Sn + kb + row)*64 + c*4);
        wr4(ktg + row*KSTR + c*4, f);
    }
    // GF cols 64..95
    #pragma unroll
    for (int i=0;i<2;i++){
        int idx = tid + 256*i, row = idx>>3, c = idx&7;
        float4 f = *(const float4*)(GF + ((size_t)bh*Sn + kb + row)*32 + c*4);
        wr4(ktg + row*KSTR + 64 + c*4, f);
    }
    // LF cols 96..127
    #pragma unroll
    for (int i=0;i<2;i++){
        int idx = tid + 256*i, row = idx>>3, c = idx&7;
        float4 f = *(const float4*)(LF + ((size_t)bh*Sn + kb + row)*32 + c*4);
        wr4(ktg + row*KSTR + 96 + c*4, f);
    }
    // mask bias col 128, zeros 129..151
    if (tid < BK){
        int mv = M[(size_t)bh*Sn + kb + tid];
        u32x4 w; w[0] = (mv == 1) ? 0x0000ceacu : 0u;  // bf16(-1e9*log2e)
        w[1]=0u; w[2]=0u; w[3]=0u;
        *(u32x4*)(ktg + tid*KSTR + 128) = w;
        u32x4 z; z[0]=0u; z[1]=0u; z[2]=0u; z[3]=0u;
        *(u32x4*)(ktg + tid*KSTR + 136) = z;
        *(u32x4*)(ktg + tid*KSTR + 144) = z;
    }
    __syncthreads();
    // Vt out: [64 d][36 dwords] (dwords 0..31 = k pairs; 32..35 pad, unread)
    #pragma unroll
    for (int i=0;i<8;i++){
        int idx = tid + 256*i, d = idx>>5, j = idx&31;
        vtg[d*36 + j] = f2bf2(vlds[d*65 + 2*j], vlds[d*65 + 2*j + 1]);
    }
}

// ---------------- main: flash attention ----------------
__global__ __launch_bounds__(256, 4)
void attn_main(const float* __restrict__ Q, const unsigned short* __restrict__ Kp,
               const unsigned short* __restrict__ Vp,
               const float* __restrict__ GF, const float* __restrict__ LF,
               float* __restrict__ O)
{
    __shared__ __align__(16) unsigned char smem[KTILE + VTILE];  // 28672 B
    unsigned short* kt_s = (unsigned short*)smem;
    unsigned short* vt_s = (unsigned short*)(smem + KTILE);

    const int tid  = threadIdx.x;
    const int wave = tid >> 6, lane = tid & 63;
    const int l31  = lane & 31, h = lane >> 5;
    const int qh   = wave >> 1;   // q-half (0,1)
    const int kp   = wave & 1;    // k-half (0,1)
    const int bh = blockIdx.x & 63;   // low bits -> same XCD for one bh
    const int qb = blockIdx.x >> 6;
    const float SCL = 0.18033688011112042f;  // 0.125 * log2(e)

    // ---- Q fragments, B-layout B[d=16*dc+8h+j][q=l31], fp32->bf16 once ----
    const int qrow = qb*BQ + qh*32 + l31;
    u32x4 qf[9];
    #pragma unroll
    for (int dc = 0; dc < 8; dc++){
        const int cb = dc*16 + 8*h;
        const float* src;
        if (cb < 64)      src = Q  + ((size_t)bh*Sn + qrow)*64 + cb;
        else if (cb < 96) src = GF + ((size_t)bh*Sn + qrow)*32 + (cb - 64);
        else              src = LF + ((size_t)bh*Sn + qrow)*32 + (cb - 96);
        float4 f0 = *(const float4*)src;
        float4 f1 = *(const float4*)(src + 4);
        qf[dc][0] = f2bf2(f0.x*SCL, f0.y*SCL);
        qf[dc][1] = f2bf2(f0.z*SCL, f0.w*SCL);
        qf[dc][2] = f2bf2(f1.x*SCL, f1.y*SCL);
        qf[dc][3] = f2bf2(f1.z*SCL, f1.w*SCL);
    }
    qf[8][0] = h ? 0u : 0x00003f80u;  // 1.0 at enriched col 128 (mask bias)
    qf[8][1] = 0u; qf[8][2] = 0u; qf[8][3] = 0u;

    f32x16 oacc[2];
    #pragma unroll
    for (int dt=0; dt<2; dt++)
        #pragma unroll
        for (int r=0; r<16; r++) oacc[dt][r] = 0.f;
    float lrun = 0.f;

    for (int t = 0; t < NT; t++){
        __syncthreads();
        // ---- async stage: 19 K chunks + 9 V chunks, 7 per wave ----
        const unsigned char* gK = (const unsigned char*)Kp + (size_t)(bh*NT + t)*KTILE;
        const unsigned char* gV = (const unsigned char*)Vp + (size_t)(bh*NT + t)*VTILE;
        #pragma unroll
        for (int i=0;i<7;i++){
            int c = wave*7 + i;
            if (c < 19) gld_lds16(gK + (size_t)c*1024 + lane*16, smem + c*1024);
            else        gld_lds16(gV + (size_t)(c-19)*1024 + lane*16,
                                  smem + KTILE + (size_t)(c-19)*1024);
        }
        __syncthreads();

        // ---- S^T(32k x 32q) for this wave's k-half ----
        f32x16 acc;
        #pragma unroll
        for (int r=0;r<16;r++) acc[r] = 0.f;
        #pragma unroll
        for (int dc=0; dc<9; dc++){
            u32x4 ar = *(const u32x4*)(kt_s + (kp*32 + l31)*KSTR + dc*16 + 8*h);
            acc = __builtin_amdgcn_mfma_f32_32x32x16_bf16(
                    __builtin_bit_cast(bf16x8, ar),
                    __builtin_bit_cast(bf16x8, qf[dc]), acc, 0, 0, 0);
        }

        // ---- no-max softmax: p = exp2(s) (masked s ~ -1.4e9 -> 0) ----
        float rs = 0.f;
        #pragma unroll
        for (int r=0;r<16;r++){
            float p = __builtin_amdgcn_exp2f(acc[r]);
            acc[r] = p; rs += p;
        }
        lrun += rs;

        // ---- P C-layout -> B-frag: pack + lane^32 half exchange ----
        unsigned pk[8], px[8];
        #pragma unroll
        for (int i=0;i<8;i++) pk[i] = pkbf(acc[2*i], acc[2*i+1]);
        #pragma unroll
        for (int i=0;i<8;i++) px[i] = (unsigned)__shfl_xor((int)pk[i], 32, 64);
        u32x4 b0, b1;
        b0[0] = h ? px[2] : pk[0];  b0[1] = h ? px[3] : pk[1];
        b0[2] = h ? pk[2] : px[0];  b0[3] = h ? pk[3] : px[1];
        b1[0] = h ? px[6] : pk[4];  b1[1] = h ? px[7] : pk[5];
        b1[2] = h ? pk[6] : px[4];  b1[3] = h ? pk[7] : px[5];

        // ---- O^T += V^T * P over this wave's 32 k ----
        #pragma unroll
        for (int dt=0;dt<2;dt++){
            u32x4 va0 = *(const u32x4*)(vt_s + (dt*32 + l31)*VSTR + kp*32 + 8*h);
            u32x4 va1 = *(const u32x4*)(vt_s + (dt*32 + l31)*VSTR + kp*32 + 16 + 8*h);
            oacc[dt] = __builtin_amdgcn_mfma_f32_32x32x16_bf16(
                    __builtin_bit_cast(bf16x8, va0),
                    __builtin_bit_cast(bf16x8, b0), oacc[dt], 0, 0, 0);
            oacc[dt] = __builtin_amdgcn_mfma_f32_32x32x16_bf16(
                    __builtin_bit_cast(bf16x8, va1),
                    __builtin_bit_cast(bf16x8, b1), oacc[dt], 0, 0, 0);
        }
    }

    // ---- epilogue: combine k-halves via LDS, normalize, coalesced store ----
    __syncthreads();
    float lw = lrun + __shfl_xor(lrun, 32, 64);    // per-q sum, this k-half
    float* s1 = (float*)smem;                      // [64 q][OSTR] f32
    float* s2 = (float*)(smem + 64*OSTR*4);        // [64] l partial (17408..)
    if (kp == 1){
        #pragma unroll
        for (int dt=0;dt<2;dt++)
            #pragma unroll
            for (int rg=0;rg<4;rg++){
                float4 w;
                w.x = oacc[dt][rg*4+0]; w.y = oacc[dt][rg*4+1];
                w.z = oacc[dt][rg*4+2]; w.w = oacc[dt][rg*4+3];
                *(float4*)(s1 + (qh*32 + l31)*OSTR + dt*32 + rg*8 + 4*h) = w;
            }
        if (h == 0) s2[qh*32 + l31] = lw;
    }
    __syncthreads();
    if (kp == 0){
        float inv = 1.0f / (lw + s2[qh*32 + l31]);
        #pragma unroll
        for (int dt=0;dt<2;dt++)
            #pragma unroll
            for (int rg=0;rg<4;rg++){
                float* p = s1 + (qh*32 + l31)*OSTR + dt*32 + rg*8 + 4*h;
                float4 w = *(float4*)p;
                w.x = (w.x + oacc[dt][rg*4+0])*inv;
                w.y = (w.y + oacc[dt][rg*4+1])*inv;
                w.z = (w.z + oacc[dt][rg*4+2])*inv;
                w.w = (w.w + oacc[dt][rg*4+3])*inv;
                *(float4*)p = w;
            }
    }
    __syncthreads();
    #pragma unroll
    for (int i=0;i<4;i++){
        int idx = tid + 256*i, r = idx>>4, c = idx&15;
        *(float4*)(O + ((size_t)bh*Sn + qb*BQ + r)*64 + c*4) =
            *(const float4*)(s1 + r*OSTR + c*4);
    }
}

extern "C" void kernel_launch(void* const* d_in, const int* in_sizes, int n_in,
                              void* d_out, int out_size, void* d_ws, size_t ws_size,
                              hipStream_t stream) {
    const float* Q  = (const float*)d_in[0];
    const float* K  = (const float*)d_in[1];
    const float* V  = (const float*)d_in[2];
    const float* LF = (const float*)d_in[3];
    const float* GF = (const float*)d_in[4];
    const int*   M  = (const int*)d_in[5];
    float* O = (float*)d_out;

    unsigned short* Kp = (unsigned short*)d_ws;                    // 19,922,944 B
    unsigned short* Vp = Kp + (size_t)BHn*NT*BK*KSTR;              // + 9,437,184 B

    attn_prep<<<dim3(BHn*NT), dim3(256), 0, stream>>>(K, V, LF, GF, M, Kp, Vp);
    attn_main<<<dim3(BHn*NT), dim3(256), 0, stream>>>(Q, Kp, Vp, GF, LF, O);
}

// Round 3
// 148.665 us; speedup vs baseline: 1.0712x; 1.0712x over previous
//
#include <hip/hip_runtime.h>
#include <hip/hip_bf16.h>

// ScaledDotProductAttentionEnriched: BH=64, S=1024, DK=64, FG=FL=32.
// Pass 1 (prep): K-enriched bf16 tiles (incl. mask-bias col, zero-padded) and
// V^T bf16 tiles with the key-permutation tau baked in (tau swaps k quads
// [4..7]<->[8..11] within each 16) written to d_ws as exact LDS images.
// Pass 2 (main): flash attention, 512-thr blocks (4 q-subtiles x 2 k-halves),
// async global_load_lds staging, no-max exp2 softmax, P C-layout feeds PV
// B-operand DIRECTLY (no cross-lane exchange, thanks to tau).

#define BHn 64
#define Sn  1024
#define NT  16
#define KSTR 144              // K-enriched row stride (bf16): 144 cols, no pad
#define VSTR 72               // Vt row stride (bf16): 64 + 8 pad (16B-aligned)
#define KTILE (64*KSTR*2)     // 18432 B = 18 KiB chunks
#define VTILE (64*VSTR*2)     // 9216 B  = 9 chunks
#define OSTR 68
#define SMEMB (128*OSTR*4 + 512)   // 35328 B (epilogue needs the most)

typedef __attribute__((ext_vector_type(8)))  __bf16 bf16x8;
typedef __attribute__((ext_vector_type(16))) float  f32x16;
typedef __attribute__((ext_vector_type(4)))  unsigned int u32x4;

__device__ __forceinline__ unsigned f2bf1(float a){
    union { float f; unsigned u; } c; c.f = a;
    return (c.u + 0x7fffu + ((c.u >> 16) & 1u)) >> 16;   // RNE f32->bf16
}
__device__ __forceinline__ unsigned f2bf2(float a, float b){
    return f2bf1(a) | (f2bf1(b) << 16);
}
// (bf16_trunc(b)<<16)|bf16_trunc(a) in one v_perm_b32
__device__ __forceinline__ unsigned pkbf(float a, float b){
    return __builtin_amdgcn_perm(__builtin_bit_cast(unsigned, b),
                                 __builtin_bit_cast(unsigned, a), 0x07060302u);
}
__device__ __forceinline__ void gld_lds16(const void* g, void* l){
    __builtin_amdgcn_global_load_lds(
        (const __attribute__((address_space(1))) unsigned int*)g,
        (__attribute__((address_space(3))) unsigned int*)l, 16, 0, 0);
}

// ---------------- prep: fp32 -> bf16 tile images, no LDS ----------------
__global__ __launch_bounds__(256)
void attn_prep(const float* __restrict__ K, const float* __restrict__ V,
               const float* __restrict__ LF, const float* __restrict__ GF,
               const int* __restrict__ M,
               unsigned short* __restrict__ Kp, unsigned short* __restrict__ Vp)
{
    const int tid = threadIdx.x;
    const int bh = blockIdx.x >> 4, ti = blockIdx.x & 15, kb = ti*64;
    unsigned short* ktg = Kp + (size_t)(bh*NT + ti) * (64*KSTR);
    unsigned int*   vtg = (unsigned int*)(Vp + (size_t)(bh*NT + ti) * (64*VSTR));

    // K cols 0..63: 64 rows x 8 col-groups of 8
    #pragma unroll
    for (int i=0;i<2;i++){
        int idx = tid + 256*i, row = idx>>3, c = idx&7;
        const float* s = K + ((size_t)bh*Sn + kb + row)*64 + c*8;
        float4 f0 = *(const float4*)s, f1 = *(const float4*)(s+4);
        u32x4 w; w[0]=f2bf2(f0.x,f0.y); w[1]=f2bf2(f0.z,f0.w);
        w[2]=f2bf2(f1.x,f1.y); w[3]=f2bf2(f1.z,f1.w);
        *(u32x4*)(ktg + row*KSTR + c*8) = w;
    }
    // GF cols 64..95
    {
        int row = tid>>2, c = tid&3;
        const float* s = GF + ((size_t)bh*Sn + kb + row)*32 + c*8;
        float4 f0 = *(const float4*)s, f1 = *(const float4*)(s+4);
        u32x4 w; w[0]=f2bf2(f0.x,f0.y); w[1]=f2bf2(f0.z,f0.w);
        w[2]=f2bf2(f1.x,f1.y); w[3]=f2bf2(f1.z,f1.w);
        *(u32x4*)(ktg + row*KSTR + 64 + c*8) = w;
    }
    // LF cols 96..127
    {
        int row = tid>>2, c = tid&3;
        const float* s = LF + ((size_t)bh*Sn + kb + row)*32 + c*8;
        float4 f0 = *(const float4*)s, f1 = *(const float4*)(s+4);
        u32x4 w; w[0]=f2bf2(f0.x,f0.y); w[1]=f2bf2(f0.z,f0.w);
        w[2]=f2bf2(f1.x,f1.y); w[3]=f2bf2(f1.z,f1.w);
        *(u32x4*)(ktg + row*KSTR + 96 + c*8) = w;
    }
    // mask-bias col 128, zeros through col 143
    if (tid < 64){
        int mv = M[(size_t)bh*Sn + kb + tid];
        u32x4 w; w[0] = (mv == 1) ? 0x0000ceacu : 0u;  // bf16(-1e9*log2e)
        w[1]=0u; w[2]=0u; w[3]=0u;
        *(u32x4*)(ktg + tid*KSTR + 128) = w;
        u32x4 z; z[0]=0u; z[1]=0u; z[2]=0u; z[3]=0u;
        *(u32x4*)(ktg + tid*KSTR + 136) = z;
    }
    // Vt with tau permutation: col k' <- key tau(k'), tau swaps quads 1<->2 per 16
    {
        int d = tid & 63, g = tid >> 6;   // g: 16-key group 0..3
        const float* vb = V + ((size_t)bh*Sn + kb + 16*g)*64 + d;
        const int pm[16] = {0,1,2,3, 8,9,10,11, 4,5,6,7, 12,13,14,15};
        unsigned w[8];
        #pragma unroll
        for (int m=0;m<8;m++)
            w[m] = f2bf2(vb[(size_t)pm[2*m]*64], vb[(size_t)pm[2*m+1]*64]);
        u32x4 a, b;
        a[0]=w[0]; a[1]=w[1]; a[2]=w[2]; a[3]=w[3];
        b[0]=w[4]; b[1]=w[5]; b[2]=w[6]; b[3]=w[7];
        *(u32x4*)(vtg + d*36 + g*8)     = a;
        *(u32x4*)(vtg + d*36 + g*8 + 4) = b;
    }
}

// ---------------- main: flash attention, 512 threads ----------------
__global__ __launch_bounds__(512, 4)
void attn_main(const float* __restrict__ Q, const unsigned short* __restrict__ Kp,
               const unsigned short* __restrict__ Vp,
               const float* __restrict__ GF, const float* __restrict__ LF,
               float* __restrict__ O)
{
    __shared__ __align__(16) unsigned char smem[SMEMB];
    unsigned short* kt_s = (unsigned short*)smem;
    unsigned short* vt_s = (unsigned short*)(smem + KTILE);

    const int tid  = threadIdx.x;
    const int wave = tid >> 6, lane = tid & 63;
    const int l31  = lane & 31, h = lane >> 5;
    const int qh   = wave >> 1;   // q-subtile 0..3
    const int kp   = wave & 1;    // k-half
    const int bh = blockIdx.x & 63;   // same-bh blocks -> same XCD
    const int qb = blockIdx.x >> 6;   // 0..7
    const float SCL = 0.18033688011112042f;  // 0.125 * log2(e)

    // Q fragments, B-layout B[d=16*dc+8h+j][q=l31]
    const int qrow = qb*128 + qh*32 + l31;
    u32x4 qf[9];
    #pragma unroll
    for (int dc = 0; dc < 8; dc++){
        const int cb = dc*16 + 8*h;
        const float* src;
        if (cb < 64)      src = Q  + ((size_t)bh*Sn + qrow)*64 + cb;
        else if (cb < 96) src = GF + ((size_t)bh*Sn + qrow)*32 + (cb - 64);
        else              src = LF + ((size_t)bh*Sn + qrow)*32 + (cb - 96);
        float4 f0 = *(const float4*)src;
        float4 f1 = *(const float4*)(src + 4);
        qf[dc][0] = f2bf2(f0.x*SCL, f0.y*SCL);
        qf[dc][1] = f2bf2(f0.z*SCL, f0.w*SCL);
        qf[dc][2] = f2bf2(f1.x*SCL, f1.y*SCL);
        qf[dc][3] = f2bf2(f1.z*SCL, f1.w*SCL);
    }
    qf[8][0] = h ? 0u : 0x00003f80u;  // 1.0 at enriched col 128 (mask bias)
    qf[8][1] = 0u; qf[8][2] = 0u; qf[8][3] = 0u;

    f32x16 oacc[2];
    #pragma unroll
    for (int dt=0; dt<2; dt++)
        #pragma unroll
        for (int r=0; r<16; r++) oacc[dt][r] = 0.f;
    float lrun = 0.f;

    for (int t = 0; t < NT; t++){
        __syncthreads();
        const unsigned char* gK = (const unsigned char*)Kp + (size_t)(bh*NT + t)*KTILE;
        const unsigned char* gV = (const unsigned char*)Vp + (size_t)(bh*NT + t)*VTILE;
        #pragma unroll
        for (int i=0;i<4;i++){
            int c = wave + 8*i;                 // wave-uniform
            if (c < 18)      gld_lds16(gK + (size_t)c*1024 + lane*16, smem + c*1024);
            else if (c < 27) gld_lds16(gV + (size_t)(c-18)*1024 + lane*16,
                                       smem + KTILE + (size_t)(c-18)*1024);
        }
        __syncthreads();

        // S^T(32k x 32q) for this wave's k-half
        f32x16 acc;
        #pragma unroll
        for (int r=0;r<16;r++) acc[r] = 0.f;
        #pragma unroll
        for (int dc=0; dc<9; dc++){
            u32x4 ar = *(const u32x4*)(kt_s + (kp*32 + l31)*KSTR + dc*16 + 8*h);
            acc = __builtin_amdgcn_mfma_f32_32x32x16_bf16(
                    __builtin_bit_cast(bf16x8, ar),
                    __builtin_bit_cast(bf16x8, qf[dc]), acc, 0, 0, 0);
        }

        // no-max softmax: p = exp2(s) (masked s ~ -1.4e9 -> 0; s_max ~ 12 safe)
        float rs = 0.f;
        #pragma unroll
        for (int r=0;r<16;r++){
            float p = __builtin_amdgcn_exp2f(acc[r]);
            acc[r] = p; rs += p;
        }
        lrun += rs;

        // P C-layout -> B-operand directly (tau-permuted Vt absorbs the swap)
        unsigned pk[8];
        #pragma unroll
        for (int i=0;i<8;i++) pk[i] = pkbf(acc[2*i], acc[2*i+1]);
        u32x4 b0, b1;
        b0[0]=pk[0]; b0[1]=pk[1]; b0[2]=pk[2]; b0[3]=pk[3];
        b1[0]=pk[4]; b1[1]=pk[5]; b1[2]=pk[6]; b1[3]=pk[7];

        // O^T += V^T * P over this wave's 32 k
        #pragma unroll
        for (int dt=0;dt<2;dt++){
            u32x4 va0 = *(const u32x4*)(vt_s + (dt*32 + l31)*VSTR + kp*32 + 8*h);
            u32x4 va1 = *(const u32x4*)(vt_s + (dt*32 + l31)*VSTR + kp*32 + 16 + 8*h);
            oacc[dt] = __builtin_amdgcn_mfma_f32_32x32x16_bf16(
                    __builtin_bit_cast(bf16x8, va0),
                    __builtin_bit_cast(bf16x8, b0), oacc[dt], 0, 0, 0);
            oacc[dt] = __builtin_amdgcn_mfma_f32_32x32x16_bf16(
                    __builtin_bit_cast(bf16x8, va1),
                    __builtin_bit_cast(bf16x8, b1), oacc[dt], 0, 0, 0);
        }
    }

    // epilogue: combine k-halves via LDS, normalize, coalesced stores
    __syncthreads();
    float lw = lrun + __shfl_xor(lrun, 32, 64);   // full 32-k sum, this k-half
    float* s1 = (float*)smem;                     // [128 q][OSTR]
    float* s2 = (float*)(smem + 128*OSTR*4);      // [128] l partials
    if (kp == 1){
        #pragma unroll
        for (int dt=0;dt<2;dt++)
            #pragma unroll
            for (int rg=0;rg<4;rg++){
                float4 w;
                w.x = oacc[dt][rg*4+0]; w.y = oacc[dt][rg*4+1];
                w.z = oacc[dt][rg*4+2]; w.w = oacc[dt][rg*4+3];
                *(float4*)(s1 + (qh*32 + l31)*OSTR + dt*32 + rg*8 + 4*h) = w;
            }
        if (h == 0) s2[qh*32 + l31] = lw;
    }
    __syncthreads();
    if (kp == 0){
        float inv = 1.0f / (lw + s2[qh*32 + l31]);
        #pragma unroll
        for (int dt=0;dt<2;dt++)
            #pragma unroll
            for (int rg=0;rg<4;rg++){
                float* p = s1 + (qh*32 + l31)*OSTR + dt*32 + rg*8 + 4*h;
                float4 w = *(float4*)p;
                w.x = (w.x + oacc[dt][rg*4+0])*inv;
                w.y = (w.y + oacc[dt][rg*4+1])*inv;
                w.z = (w.z + oacc[dt][rg*4+2])*inv;
                w.w = (w.w + oacc[dt][rg*4+3])*inv;
                *(float4*)p = w;
            }
    }
    __syncthreads();
    #pragma unroll
    for (int i=0;i<4;i++){
        int idx = tid + 512*i, r = idx>>4, c = idx&15;
        *(float4*)(O + ((size_t)bh*Sn + qb*128 + r)*64 + c*4) =
            *(const float4*)(s1 + r*OSTR + c*4);
    }
}

extern "C" void kernel_launch(void* const* d_in, const int* in_sizes, int n_in,
                              void* d_out, int out_size, void* d_ws, size_t ws_size,
                              hipStream_t stream) {
    const float* Q  = (const float*)d_in[0];
    const float* K  = (const float*)d_in[1];
    const float* V  = (const float*)d_in[2];
    const float* LF = (const float*)d_in[3];
    const float* GF = (const float*)d_in[4];
    const int*   M  = (const int*)d_in[5];
    float* O = (float*)d_out;

    unsigned short* Kp = (unsigned short*)d_ws;            // 18,874,368 B
    unsigned short* Vp = Kp + (size_t)BHn*NT*64*KSTR;      // + 9,437,184 B

    attn_prep<<<dim3(BHn*NT), dim3(256), 0, stream>>>(K, V, LF, GF, M, Kp, Vp);
    attn_main<<<dim3(BHn*(Sn/128)), dim3(512), 0, stream>>>(Q, Kp, Vp, GF, LF, O);
}

// Round 5
// 143.524 us; speedup vs baseline: 1.1096x; 1.0358x over previous
//
#include <hip/hip_runtime.h>
#include <hip/hip_bf16.h>

// ScaledDotProductAttentionEnriched: BH=64, S=1024, DK=64, FG=FL=32.
// Pass 1 (prep): K-enriched bf16 tiles (mask-bias col baked in, zero pad to
// 152-col stride -> conflict-free b128 frag reads) and tau-permuted V^T bf16
// tiles written to d_ws as exact LDS images.
// Pass 2 (main): flash attention, 512-thr blocks (4 q-subtiles x 2 k-halves),
// double-buffered async global_load_lds staging. Correctness of the pipeline
// is enforced by an EXPLICIT s_waitcnt vmcnt(0) at the end of each iteration
// (the compiler does not reliably drain LDS-DMA at s_barrier when the loads
// are issued after the previous barrier): every wave arrives at the top-of-
// loop barrier with its own DMA landed, so barrier release implies tile-t is
// fully in LDS. The drain sits AFTER compute-t, so DMA latency stays hidden.

#define BHn 64
#define Sn  1024
#define NT  16
#define KSTR 152              // K-enriched row stride (bf16): 76 dwords = 12 mod 32
#define VSTR 72               // Vt row stride (bf16): 36 dwords = 4 mod 32
#define KTILE (64*KSTR*2)     // 19456 B = 19 chunks of 1024
#define VTILE (64*VSTR*2)     // 9216 B  = 9 chunks
#define BUFSZ (KTILE+VTILE)   // 28672 B
#define OSTR 68
// s_waitcnt imm: vmcnt=0, expcnt=7 (no wait), lgkmcnt=15 (no wait)
#define WAIT_VM0 0x0F70

typedef __attribute__((ext_vector_type(8)))  __bf16 bf16x8;
typedef __attribute__((ext_vector_type(16))) float  f32x16;
typedef __attribute__((ext_vector_type(4)))  unsigned int u32x4;

__device__ __forceinline__ unsigned f2bf1(float a){
    union { float f; unsigned u; } c; c.f = a;
    return (c.u + 0x7fffu + ((c.u >> 16) & 1u)) >> 16;   // RNE f32->bf16
}
__device__ __forceinline__ unsigned f2bf2(float a, float b){
    return f2bf1(a) | (f2bf1(b) << 16);
}
// (bf16_trunc(b)<<16)|bf16_trunc(a) in one v_perm_b32
__device__ __forceinline__ unsigned pkbf(float a, float b){
    return __builtin_amdgcn_perm(__builtin_bit_cast(unsigned, b),
                                 __builtin_bit_cast(unsigned, a), 0x07060302u);
}
__device__ __forceinline__ void gld_lds16(const void* g, void* l){
    __builtin_amdgcn_global_load_lds(
        (const __attribute__((address_space(1))) unsigned int*)g,
        (__attribute__((address_space(3))) unsigned int*)l, 16, 0, 0);
}

// ---------------- prep: fp32 -> bf16 tile images, no LDS ----------------
__global__ __launch_bounds__(256)
void attn_prep(const float* __restrict__ K, const float* __restrict__ V,
               const float* __restrict__ LF, const float* __restrict__ GF,
               const int* __restrict__ M,
               unsigned short* __restrict__ Kp, unsigned short* __restrict__ Vp)
{
    const int tid = threadIdx.x;
    const int bh = blockIdx.x >> 4, ti = blockIdx.x & 15, kb = ti*64;
    unsigned short* ktg = Kp + (size_t)(bh*NT + ti) * (64*KSTR);
    unsigned int*   vtg = (unsigned int*)(Vp + (size_t)(bh*NT + ti) * (64*VSTR));

    // K cols 0..63: 64 rows x 8 col-groups of 8
    #pragma unroll
    for (int i=0;i<2;i++){
        int idx = tid + 256*i, row = idx>>3, c = idx&7;
        const float* s = K + ((size_t)bh*Sn + kb + row)*64 + c*8;
        float4 f0 = *(const float4*)s, f1 = *(const float4*)(s+4);
        u32x4 w; w[0]=f2bf2(f0.x,f0.y); w[1]=f2bf2(f0.z,f0.w);
        w[2]=f2bf2(f1.x,f1.y); w[3]=f2bf2(f1.z,f1.w);
        *(u32x4*)(ktg + row*KSTR + c*8) = w;
    }
    // GF cols 64..95
    {
        int row = tid>>2, c = tid&3;
        const float* s = GF + ((size_t)bh*Sn + kb + row)*32 + c*8;
        float4 f0 = *(const float4*)s, f1 = *(const float4*)(s+4);
        u32x4 w; w[0]=f2bf2(f0.x,f0.y); w[1]=f2bf2(f0.z,f0.w);
        w[2]=f2bf2(f1.x,f1.y); w[3]=f2bf2(f1.z,f1.w);
        *(u32x4*)(ktg + row*KSTR + 64 + c*8) = w;
    }
    // LF cols 96..127
    {
        int row = tid>>2, c = tid&3;
        const float* s = LF + ((size_t)bh*Sn + kb + row)*32 + c*8;
        float4 f0 = *(const float4*)s, f1 = *(const float4*)(s+4);
        u32x4 w; w[0]=f2bf2(f0.x,f0.y); w[1]=f2bf2(f0.z,f0.w);
        w[2]=f2bf2(f1.x,f1.y); w[3]=f2bf2(f1.z,f1.w);
        *(u32x4*)(ktg + row*KSTR + 96 + c*8) = w;
    }
    // mask-bias col 128, zeros through col 151
    if (tid < 64){
        int mv = M[(size_t)bh*Sn + kb + tid];
        u32x4 w; w[0] = (mv == 1) ? 0x0000ceacu : 0u;  // bf16(-1e9*log2e)
        w[1]=0u; w[2]=0u; w[3]=0u;
        *(u32x4*)(ktg + tid*KSTR + 128) = w;
        u32x4 z; z[0]=0u; z[1]=0u; z[2]=0u; z[3]=0u;
        *(u32x4*)(ktg + tid*KSTR + 136) = z;
        *(u32x4*)(ktg + tid*KSTR + 144) = z;
    }
    // Vt with tau permutation: col k' <- key tau(k'), tau swaps quads 1<->2 per 16
    {
        int d = tid & 63, g = tid >> 6;   // g: 16-key group 0..3
        const float* vb = V + ((size_t)bh*Sn + kb + 16*g)*64 + d;
        const int pm[16] = {0,1,2,3, 8,9,10,11, 4,5,6,7, 12,13,14,15};
        unsigned w[8];
        #pragma unroll
        for (int m=0;m<8;m++)
            w[m] = f2bf2(vb[(size_t)pm[2*m]*64], vb[(size_t)pm[2*m+1]*64]);
        u32x4 a, b;
        a[0]=w[0]; a[1]=w[1]; a[2]=w[2]; a[3]=w[3];
        b[0]=w[4]; b[1]=w[5]; b[2]=w[6]; b[3]=w[7];
        *(u32x4*)(vtg + d*36 + g*8)     = a;
        *(u32x4*)(vtg + d*36 + g*8 + 4) = b;
    }
}

// ---------------- main: flash attention, 512 threads, LDS dbuf ----------------
__global__ __launch_bounds__(512, 4)
void attn_main(const float* __restrict__ Q, const unsigned short* __restrict__ Kp,
               const unsigned short* __restrict__ Vp,
               const float* __restrict__ GF, const float* __restrict__ LF,
               float* __restrict__ O)
{
    __shared__ __align__(16) unsigned char smem[2*BUFSZ];   // 57344 B
    const int tid  = threadIdx.x;
    const int wave = tid >> 6, lane = tid & 63;
    const int l31  = lane & 31, h = lane >> 5;
    const int qh   = wave >> 1;   // q-subtile 0..3
    const int kp   = wave & 1;    // k-half
    const int bh = blockIdx.x & 63;   // same-bh blocks -> same XCD
    const int qb = blockIdx.x >> 6;   // 0..7
    const float SCL = 0.18033688011112042f;  // 0.125 * log2(e)

    // Q fragments, B-layout B[d=16*dc+8h+j][q=l31]
    const int qrow = qb*128 + qh*32 + l31;
    u32x4 qf[9];
    #pragma unroll
    for (int dc = 0; dc < 8; dc++){
        const int cb = dc*16 + 8*h;
        const float* src;
        if (cb < 64)      src = Q  + ((size_t)bh*Sn + qrow)*64 + cb;
        else if (cb < 96) src = GF + ((size_t)bh*Sn + qrow)*32 + (cb - 64);
        else              src = LF + ((size_t)bh*Sn + qrow)*32 + (cb - 96);
        float4 f0 = *(const float4*)src;
        float4 f1 = *(const float4*)(src + 4);
        qf[dc][0] = f2bf2(f0.x*SCL, f0.y*SCL);
        qf[dc][1] = f2bf2(f0.z*SCL, f0.w*SCL);
        qf[dc][2] = f2bf2(f1.x*SCL, f1.y*SCL);
        qf[dc][3] = f2bf2(f1.z*SCL, f1.w*SCL);
    }
    qf[8][0] = h ? 0u : 0x00003f80u;  // 1.0 at enriched col 128 (mask bias)
    qf[8][1] = 0u; qf[8][2] = 0u; qf[8][3] = 0u;

    f32x16 oacc[2];
    #pragma unroll
    for (int dt=0; dt<2; dt++)
        #pragma unroll
        for (int r=0; r<16; r++) oacc[dt][r] = 0.f;
    float lrun = 0.f;

    const unsigned char* gKb = (const unsigned char*)Kp + (size_t)bh*NT*KTILE;
    const unsigned char* gVb = (const unsigned char*)Vp + (size_t)bh*NT*VTILE;

    // prologue: stage tile 0 into buffer 0, drain before first barrier
    {
        #pragma unroll
        for (int i=0;i<4;i++){
            int c = wave + 8*i;
            if (c < 19)      gld_lds16(gKb + (size_t)c*1024 + lane*16, smem + c*1024);
            else if (c < 28) gld_lds16(gVb + (size_t)(c-19)*1024 + lane*16,
                                       smem + KTILE + (size_t)(c-19)*1024);
        }
    }
    __builtin_amdgcn_s_waitcnt(WAIT_VM0);   // my tile-0 DMA has landed

    for (int t = 0; t < NT; t++){
        unsigned char* cur = smem + (size_t)(t&1)*BUFSZ;
        unsigned char* nxt = smem + (size_t)((t+1)&1)*BUFSZ;
        // invariant: every wave arrives here with vmcnt==0 (its DMA landed),
        // so after this barrier tile t is fully in LDS for all waves; and all
        // waves' reads of nxt (iteration t-1) are complete (consumed pre-MFMA).
        __syncthreads();
        if (t+1 < NT){
            const unsigned char* gK = gKb + (size_t)(t+1)*KTILE;
            const unsigned char* gV = gVb + (size_t)(t+1)*VTILE;
            #pragma unroll
            for (int i=0;i<4;i++){
                int c = wave + 8*i;
                if (c < 19)      gld_lds16(gK + (size_t)c*1024 + lane*16, nxt + c*1024);
                else if (c < 28) gld_lds16(gV + (size_t)(c-19)*1024 + lane*16,
                                           nxt + KTILE + (size_t)(c-19)*1024);
            }
        }
        unsigned short* kt_s = (unsigned short*)cur;
        unsigned short* vt_s = (unsigned short*)(cur + KTILE);

        // S^T(32k x 32q) for this wave's k-half
        f32x16 acc;
        #pragma unroll
        for (int r=0;r<16;r++) acc[r] = 0.f;
        #pragma unroll
        for (int dc=0; dc<9; dc++){
            u32x4 ar = *(const u32x4*)(kt_s + (kp*32 + l31)*KSTR + dc*16 + 8*h);
            acc = __builtin_amdgcn_mfma_f32_32x32x16_bf16(
                    __builtin_bit_cast(bf16x8, ar),
                    __builtin_bit_cast(bf16x8, qf[dc]), acc, 0, 0, 0);
        }

        // no-max softmax: p = exp2(s) (masked s ~ -1.4e9 -> 0; s_max ~ 12 safe)
        float rs = 0.f;
        #pragma unroll
        for (int r=0;r<16;r++){
            float p = __builtin_amdgcn_exp2f(acc[r]);
            acc[r] = p; rs += p;
        }
        lrun += rs;

        // P C-layout -> B-operand directly (tau-permuted Vt absorbs the swap)
        unsigned pk[8];
        #pragma unroll
        for (int i=0;i<8;i++) pk[i] = pkbf(acc[2*i], acc[2*i+1]);
        u32x4 b0, b1;
        b0[0]=pk[0]; b0[1]=pk[1]; b0[2]=pk[2]; b0[3]=pk[3];
        b1[0]=pk[4]; b1[1]=pk[5]; b1[2]=pk[6]; b1[3]=pk[7];

        // O^T += V^T * P over this wave's 32 k
        #pragma unroll
        for (int dt=0;dt<2;dt++){
            u32x4 va0 = *(const u32x4*)(vt_s + (dt*32 + l31)*VSTR + kp*32 + 8*h);
            u32x4 va1 = *(const u32x4*)(vt_s + (dt*32 + l31)*VSTR + kp*32 + 16 + 8*h);
            oacc[dt] = __builtin_amdgcn_mfma_f32_32x32x16_bf16(
                    __builtin_bit_cast(bf16x8, va0),
                    __builtin_bit_cast(bf16x8, b0), oacc[dt], 0, 0, 0);
            oacc[dt] = __builtin_amdgcn_mfma_f32_32x32x16_bf16(
                    __builtin_bit_cast(bf16x8, va1),
                    __builtin_bit_cast(bf16x8, b1), oacc[dt], 0, 0, 0);
        }

        // drain my prefetch (t+1) AFTER compute-t hid its latency
        __builtin_amdgcn_s_waitcnt(WAIT_VM0);
    }

    // epilogue: combine k-halves via LDS, normalize, coalesced stores
    __syncthreads();
    float lw = lrun + __shfl_xor(lrun, 32, 64);   // full 32-k sum, this k-half
    float* s1 = (float*)smem;                     // [128 q][OSTR]
    float* s2 = (float*)(smem + 128*OSTR*4);      // [128] l partials
    if (kp == 1){
        #pragma unroll
        for (int dt=0;dt<2;dt++)
            #pragma unroll
            for (int rg=0;rg<4;rg++){
                float4 w;
                w.x = oacc[dt][rg*4+0]; w.y = oacc[dt][rg*4+1];
                w.z = oacc[dt][rg*4+2]; w.w = oacc[dt][rg*4+3];
                *(float4*)(s1 + (qh*32 + l31)*OSTR + dt*32 + rg*8 + 4*h) = w;
            }
        if (h == 0) s2[qh*32 + l31] = lw;
    }
    __syncthreads();
    if (kp == 0){
        float inv = 1.0f / (lw + s2[qh*32 + l31]);
        #pragma unroll
        for (int dt=0;dt<2;dt++)
            #pragma unroll
            for (int rg=0;rg<4;rg++){
                float* p = s1 + (qh*32 + l31)*OSTR + dt*32 + rg*8 + 4*h;
                float4 w = *(float4*)p;
                w.x = (w.x + oacc[dt][rg*4+0])*inv;
                w.y = (w.y + oacc[dt][rg*4+1])*inv;
                w.z = (w.z + oacc[dt][rg*4+2])*inv;
                w.w = (w.w + oacc[dt][rg*4+3])*inv;
                *(float4*)p = w;
            }
    }
    __syncthreads();
    #pragma unroll
    for (int i=0;i<4;i++){
        int idx = tid + 512*i, r = idx>>4, c = idx&15;
        *(float4*)(O + ((size_t)bh*Sn + qb*128 + r)*64 + c*4) =
            *(const float4*)(s1 + r*OSTR + c*4);
    }
}

extern "C" void kernel_launch(void* const* d_in, const int* in_sizes, int n_in,
                              void* d_out, int out_size, void* d_ws, size_t ws_size,
                              hipStream_t stream) {
    const float* Q  = (const float*)d_in[0];
    const float* K  = (const float*)d_in[1];
    const float* V  = (const float*)d_in[2];
    const float* LF = (const float*)d_in[3];
    const float* GF = (const float*)d_in[4];
    const int*   M  = (const int*)d_in[5];
    float* O = (float*)d_out;

    unsigned short* Kp = (unsigned short*)d_ws;            // 19,922,944 B
    unsigned short* Vp = Kp + (size_t)BHn*NT*64*KSTR;      // + 9,437,184 B

    attn_prep<<<dim3(BHn*NT), dim3(256), 0, stream>>>(K, V, LF, GF, M, Kp, Vp);
    attn_main<<<dim3(BHn*(Sn/128)), dim3(512), 0, stream>>>(Q, Kp, Vp, GF, LF, O);
}